// Round 11
// baseline (33.539 us; speedup 1.0000x reference)
//
#include <hip/hip_runtime.h>

// RuleNet: out[b] = 5 + sum_c rw[c] * min_j( mu[c,j]*x[b,j] + (1-mu[c,j]) )
// with x = [x0, 1-x0], mu = sigmoid(conjunctions).
// Rewrite: fit(b,c) = 1 - max_v max( mu1[c,v]*(1-x0[b,v]), mu2[c,v]*x0[b,v] )
//          mu1*(1-x) = fma(-mu1, x, mu1).
//
// R11: lane = v (4 v per lane). x is LANE-LOCAL registers (no LDS, no
// broadcast at all); mu read in natural [c][2V] layout, coalesced, depth-1
// prefetch in named regs. Cross-lane max amortized: 3 butterfly levels on
// 8 bi + 7-cndmask mux + 3 levels on 1 value. No barrier in hot loop ->
// no wave phase-lock (R6-R10 lesson: pipe serialization under lockstep).

#define B_    1024
#define C_    512
#define V_    256
#define TWOV  512

#define WAVES  8
#define BPB    8               // batches per block
#define NBG    (B_ / BPB)      // 128 b-groups
#define CSPLIT 4               // c-splits
#define CPB    (C_ / CSPLIT)   // 128 c per block
#define CPWV   (CPB / WAVES)   // 16 c per wave

// ---------- kernel 1: elementwise sigmoid (coalesced), + out=5.0 init ----------
__global__ __launch_bounds__(256) void k_prep(const float* __restrict__ conj,
                                              float* __restrict__ mu,
                                              float* __restrict__ out) {
    const int i = blockIdx.x * 256 + threadIdx.x;     // 65536 float4s
    if (blockIdx.x < 4) out[blockIdx.x * 256 + threadIdx.x] = 5.0f;
    float4 z = reinterpret_cast<const float4*>(conj)[i];
    float4 r;
    r.x = 1.0f / (1.0f + __expf(-z.x));
    r.y = 1.0f / (1.0f + __expf(-z.y));
    r.z = 1.0f / (1.0f + __expf(-z.z));
    r.w = 1.0f / (1.0f + __expf(-z.w));
    reinterpret_cast<float4*>(mu)[i] = r;
}

// ---------- kernel 2: main fuzzy-AND, lane = v ----------
__global__ __launch_bounds__(512, 4) void k_main(const float* __restrict__ x0,
                                                 const float* __restrict__ mu,
                                                 const float* __restrict__ rw,
                                                 float* __restrict__ out) {
    const int tid  = threadIdx.x;
    const int lane = tid & 63;
    const int wave = tid >> 6;
    const int bg   = blockIdx.x;                 // 128 groups of 8 batches
    const int cs   = blockIdx.y;                 // 4 c-splits
    const int c0   = cs * CPB + wave * CPWV;     // this wave's 16 conjunctions

    // lane-local x: v = 4*lane .. 4*lane+3 for 8 batches (coalesced, once)
    float4 xr[8];
    {
        const float* xb = x0 + (size_t)bg * BPB * V_ + lane * 4;
#pragma unroll
        for (int bi = 0; bi < BPB; ++bi)
            xr[bi] = *reinterpret_cast<const float4*>(xb + bi * V_);
    }

    // mu in natural [c][2V] layout: per c, two coalesced 1KB/wave loads
    const float* m1p = mu + (size_t)c0 * TWOV + lane * 4;

    float4 A = *reinterpret_cast<const float4*>(m1p);        // mu1, 4 v
    float4 Q = *reinterpret_cast<const float4*>(m1p + V_);   // mu2, 4 v
    float  W = rw[c0];

    float acc = 0.0f;

#pragma unroll
    for (int cc = 0; cc < CPWV; ++cc) {
        // depth-1 prefetch of next c (issued before the pin of current)
        float4 An, Qn; float Wn;
        if (cc + 1 < CPWV) {
            const float* p = m1p + (size_t)(cc + 1) * TWOV;
            An = *reinterpret_cast<const float4*>(p);
            Qn = *reinterpret_cast<const float4*>(p + V_);
            Wn = rw[c0 + cc + 1];
        }
        // pin current AFTER next issue: compiler emits graded vmcnt (waits
        // only current's loads; next's stay in flight)
        asm volatile("" : "+v"(A.x), "+v"(A.y), "+v"(A.z), "+v"(A.w),
                          "+v"(Q.x), "+v"(Q.y), "+v"(Q.z), "+v"(Q.w));

        // per-bi max over this lane's 4 v (8 independent chains = ILP)
        float m0, m1, m2, m3, m4, m5, m6, m7;
#define BI(i, M) { float4 xv = xr[i]; \
        M = fmaxf(__builtin_fmaf(-A.x, xv.x, A.x), Q.x * xv.x); \
        M = fmaxf(M, fmaxf(__builtin_fmaf(-A.y, xv.y, A.y), Q.y * xv.y)); \
        M = fmaxf(M, fmaxf(__builtin_fmaf(-A.z, xv.z, A.z), Q.z * xv.z)); \
        M = fmaxf(M, fmaxf(__builtin_fmaf(-A.w, xv.w, A.w), Q.w * xv.w)); }
        BI(0, m0) BI(1, m1) BI(2, m2) BI(3, m3)
        BI(4, m4) BI(5, m5) BI(6, m6) BI(7, m7)
#undef BI

        // butterfly levels 1,2,4: reduce each bi over its 8-lane group (32 v)
#define RED3(M) \
        M = fmaxf(M, __shfl_xor(M, 1, 64)); \
        M = fmaxf(M, __shfl_xor(M, 2, 64)); \
        M = fmaxf(M, __shfl_xor(M, 4, 64));
        RED3(m0) RED3(m1) RED3(m2) RED3(m3)
        RED3(m4) RED3(m5) RED3(m6) RED3(m7)
#undef RED3

        // mux: s = m[lane & 7] (7 cndmask, masks loop-invariant)
        float t0 = (lane & 1) ? m1 : m0;
        float t1 = (lane & 1) ? m3 : m2;
        float t2 = (lane & 1) ? m5 : m4;
        float t3 = (lane & 1) ? m7 : m6;
        float u0 = (lane & 2) ? t1 : t0;
        float u1 = (lane & 2) ? t3 : t2;
        float s  = (lane & 4) ? u1 : u0;

        // levels 8,16,32: reduce across the eight 8-lane groups (all 256 v)
        s = fmaxf(s, __shfl_xor(s, 8, 64));
        s = fmaxf(s, __shfl_xor(s, 16, 64));
        s = fmaxf(s, __shfl_xor(s, 32, 64));

        // lanes with equal (lane&7) hold identical s for batch bi = lane&7
        acc = __builtin_fmaf(W, 1.0f - s, acc);

        if (cc + 1 < CPWV) { A = An; Q = Qn; W = Wn; }
    }

    // block combine (tiny LDS), then one atomic per (block, batch)
    __shared__ float red[WAVES * 8];
    if (lane < 8) red[wave * 8 + lane] = acc;
    __syncthreads();
    if (tid < 8) {
        float s = 0.0f;
#pragma unroll
        for (int w = 0; w < WAVES; ++w) s += red[w * 8 + tid];
        atomicAdd(&out[bg * BPB + tid], s);   // 4 adds per element (c-splits)
    }
}

// ---------- fallback (ws too small): naive but correct ----------
__global__ __launch_bounds__(256) void k_naive(const float* __restrict__ x0,
                                               const float* __restrict__ conj,
                                               const float* __restrict__ rw,
                                               float* __restrict__ out) {
    int b = blockIdx.x;
    int t = threadIdx.x;
    __shared__ float red[256];
    float acc = 0.0f;
    for (int c = t; c < C_; c += 256) {
        float m = 0.0f;
        for (int v = 0; v < V_; ++v) {
            float mu1 = 1.0f / (1.0f + expf(-conj[(size_t)c * TWOV + v]));
            float mu2 = 1.0f / (1.0f + expf(-conj[(size_t)c * TWOV + V_ + v]));
            float x = x0[(size_t)b * V_ + v];
            m = fmaxf(m, fmaxf(mu1 * (1.0f - x), mu2 * x));
        }
        acc += rw[c] * (1.0f - m);
    }
    red[t] = acc;
    __syncthreads();
    for (int s = 128; s > 0; s >>= 1) {
        if (t < s) red[t] += red[t + s];
        __syncthreads();
    }
    if (t == 0) out[b] = 5.0f + red[0];
}

extern "C" void kernel_launch(void* const* d_in, const int* in_sizes, int n_in,
                              void* d_out, int out_size, void* d_ws, size_t ws_size,
                              hipStream_t stream) {
    const float* x0   = (const float*)d_in[0];
    const float* conj = (const float*)d_in[1];
    const float* rw   = (const float*)d_in[2];
    float* out = (float*)d_out;

    const size_t mu_floats = (size_t)C_ * TWOV;   // 262144 floats (1 MB)
    const size_t need = mu_floats * sizeof(float);

    if (ws_size < need) {
        k_naive<<<B_, 256, 0, stream>>>(x0, conj, rw, out);
        return;
    }

    float* mu = (float*)d_ws;

    k_prep<<<(C_ * TWOV) / (256 * 4), 256, 0, stream>>>(conj, mu, out);
    dim3 grid(NBG, CSPLIT);   // 128 x 4 = 512 blocks = 2/CU, 16 waves/CU
    k_main<<<grid, 512, 0, stream>>>(x0, mu, rw, out);
}

// Round 12
// 22.025 us; speedup vs baseline: 1.5228x; 1.5228x over previous
//
#include <hip/hip_runtime.h>

// RuleNet: out[b] = 5 + sum_c rw[c] * min_j( mu[c,j]*x[b,j] + (1-mu[c,j]) )
// with x = [x0, 1-x0], mu = sigmoid(conjunctions).
// Rewrite: fit(b,c) = 1 - max_v max( mu1[c,v]*(1-x0[b,v]), mu2[c,v]*x0[b,v] )
//          mu1*(1-x) = fma(-mu1, x, mu1).
//
// R12: x via the SCALAR pipe (s_load_dwordx4, uniform base + compile-time
// immediate offsets, SGPR double-buffer, depth-1 prefetch). mu coalesced
// VMEM (R8 transposed layout), depth-1 prefetch, consume-time pin. Hot loop
// has ZERO LDS ops, ZERO barriers, ZERO shuffles: VALU + 2 VMEM + 8 SMEM
// per 96-VALU step. v-quarters combined once in a small LDS epilogue.

#define B_    1024
#define C_    512
#define V_    256
#define TWOV  512

#define BPB    8               // batches per block
#define NBG    (B_ / BPB)      // 128 b-groups
#define NCH    4               // c-chunks of 128
#define WAVES  8               // 2 c-halves x 4 v-quarters

// ---------- kernel 1: sigmoid + transpose (R8 layout), + out=5.0 init ----------
// float4 muT4[vp][c] = (mu1[2vp], mu2[2vp], mu1[2vp+1], mu2[2vp+1]), vp row stride C_
__global__ __launch_bounds__(256) void k_prep(const float* __restrict__ conj,
                                              float2* __restrict__ muT2,
                                              float* __restrict__ out) {
    const int c = blockIdx.x;        // 512 blocks
    const int v = threadIdx.x;       // 256 threads, coalesced loads
    if (c < 4) out[c * 256 + v] = 5.0f;   // init accumulator target
    float z1 = conj[(size_t)c * TWOV + v];
    float z2 = conj[(size_t)c * TWOV + V_ + v];
    float m1 = 1.0f / (1.0f + __expf(-z1));
    float m2 = 1.0f / (1.0f + __expf(-z2));
    muT2[(size_t)(v >> 1) * (2 * C_) + c * 2 + (v & 1)] = make_float2(m1, m2);
}

// ---------- kernel 2: main fuzzy-AND ----------
__global__ __launch_bounds__(512, 4) void k_main(const float* __restrict__ x0,
                                                 const float4* __restrict__ muT4,
                                                 const float* __restrict__ rw,
                                                 float* __restrict__ out) {
    const int tid    = threadIdx.x;
    const int lane   = tid & 63;
    const int wave_u = __builtin_amdgcn_readfirstlane(tid >> 6);  // uniform
    const int t      = wave_u & 1;               // c-half (64 c)
    const int s      = wave_u >> 1;              // v-quarter (64 v)
    const int bg     = blockIdx.x;               // 128 groups of 8 batches
    const int chunk  = blockIdx.y;               // 4 chunks of 128 c
    const int c      = chunk * 128 + t * 64 + lane;
    const int v0     = s * 64;

    // uniform x base: all loads below are s_load with immediate offsets
    const float* xb = x0 + (size_t)bg * BPB * V_ + v0;

    // per-lane mu pointers (coalesced across lanes; 2 vp rows per 4-v step)
    const float4* mu1p = muT4 + (size_t)(v0 >> 1) * C_ + c;
    const float4* mu2p = mu1p + C_;

    const float rwc = rw[c];

    float m[BPB];
#pragma unroll
    for (int i = 0; i < BPB; ++i) m[i] = 0.0f;

    float4 XA0, XA1, XA2, XA3, XA4, XA5, XA6, XA7;
    float4 XB0, XB1, XB2, XB3, XB4, XB5, XB6, XB7;
    float4 ma0, mb0, ma1, mb1;

#define XL(X, q) do { \
    X##0 = *reinterpret_cast<const float4*>(xb + 0 * V_ + 4 * (q)); \
    X##1 = *reinterpret_cast<const float4*>(xb + 1 * V_ + 4 * (q)); \
    X##2 = *reinterpret_cast<const float4*>(xb + 2 * V_ + 4 * (q)); \
    X##3 = *reinterpret_cast<const float4*>(xb + 3 * V_ + 4 * (q)); \
    X##4 = *reinterpret_cast<const float4*>(xb + 4 * V_ + 4 * (q)); \
    X##5 = *reinterpret_cast<const float4*>(xb + 5 * V_ + 4 * (q)); \
    X##6 = *reinterpret_cast<const float4*>(xb + 6 * V_ + 4 * (q)); \
    X##7 = *reinterpret_cast<const float4*>(xb + 7 * V_ + 4 * (q)); \
} while (0)

#define MUL_NEXT(MA, MB) do { \
    MA = mu1p[0]; MB = mu2p[0]; mu1p += 2 * C_; mu2p += 2 * C_; \
} while (0)

#define PINM(MA, MB) \
    asm volatile("" : "+v"(MA.x), "+v"(MA.y), "+v"(MA.z), "+v"(MA.w), \
                      "+v"(MB.x), "+v"(MB.y), "+v"(MB.z), "+v"(MB.w))

#define CB(XV, MA, MB, bi) do { \
    float mm = m[bi]; \
    mm = fmaxf(fmaxf(__builtin_fmaf(-(MA).x, (XV).x, (MA).x), (MA).y * (XV).x), mm); \
    mm = fmaxf(fmaxf(__builtin_fmaf(-(MA).z, (XV).y, (MA).z), (MA).w * (XV).y), mm); \
    mm = fmaxf(fmaxf(__builtin_fmaf(-(MB).x, (XV).z, (MB).x), (MB).y * (XV).z), mm); \
    mm = fmaxf(fmaxf(__builtin_fmaf(-(MB).z, (XV).w, (MB).z), (MB).w * (XV).w), mm); \
    m[bi] = mm; } while (0)

#define COMPUTE(X, MA, MB) do { \
    CB(X##0, MA, MB, 0); CB(X##1, MA, MB, 1); \
    CB(X##2, MA, MB, 2); CB(X##3, MA, MB, 3); \
    CB(X##4, MA, MB, 4); CB(X##5, MA, MB, 5); \
    CB(X##6, MA, MB, 6); CB(X##7, MA, MB, 7); } while (0)

    // prologue: q=0 operands in flight
    XL(XA, 0);
    MUL_NEXT(ma0, mb0);

#define QSTEP(q, XC, XN, MAC, MBC, MAN, MBN) do { \
    XL(XN, (q) + 1);              /* prefetch next x quad (SMEM) */ \
    MUL_NEXT(MAN, MBN);           /* prefetch next mu (VMEM) */ \
    PINM(MAC, MBC);               /* graded vmcnt: only current mu */ \
    COMPUTE(XC, MAC, MBC); } while (0)

    QSTEP( 0, XA, XB, ma0, mb0, ma1, mb1);
    QSTEP( 1, XB, XA, ma1, mb1, ma0, mb0);
    QSTEP( 2, XA, XB, ma0, mb0, ma1, mb1);
    QSTEP( 3, XB, XA, ma1, mb1, ma0, mb0);
    QSTEP( 4, XA, XB, ma0, mb0, ma1, mb1);
    QSTEP( 5, XB, XA, ma1, mb1, ma0, mb0);
    QSTEP( 6, XA, XB, ma0, mb0, ma1, mb1);
    QSTEP( 7, XB, XA, ma1, mb1, ma0, mb0);
    QSTEP( 8, XA, XB, ma0, mb0, ma1, mb1);
    QSTEP( 9, XB, XA, ma1, mb1, ma0, mb0);
    QSTEP(10, XA, XB, ma0, mb0, ma1, mb1);
    QSTEP(11, XB, XA, ma1, mb1, ma0, mb0);
    QSTEP(12, XA, XB, ma0, mb0, ma1, mb1);
    QSTEP(13, XB, XA, ma1, mb1, ma0, mb0);
    QSTEP(14, XA, XB, ma0, mb0, ma1, mb1);
    // last step: no prefetch (avoid OOB reads past x0 / muT4)
    PINM(ma1, mb1);
    COMPUTE(XB, ma1, mb1);

#undef QSTEP
#undef COMPUTE
#undef CB
#undef PINM
#undef MUL_NEXT
#undef XL

    // ---- epilogue: combine v-quarters, weight, sum over c, accumulate ----
    __shared__ float red[4 * 128 * 9];           // 18 KB, pad 9 vs conflicts
    const int ci = t * 64 + lane;                // 0..127 within chunk
#pragma unroll
    for (int bi = 0; bi < BPB; ++bi)
        red[(s * 128 + ci) * 9 + bi] = m[bi];
    __syncthreads();

    if (wave_u < 2) {                            // wave w handles c-half t = w
        float con0, con1, con2, con3, con4, con5, con6, con7;
#define FIN(bi, CON) do { \
        float mm = red[(0 * 128 + ci) * 9 + bi]; \
        mm = fmaxf(mm, red[(1 * 128 + ci) * 9 + bi]); \
        mm = fmaxf(mm, red[(2 * 128 + ci) * 9 + bi]); \
        mm = fmaxf(mm, red[(3 * 128 + ci) * 9 + bi]); \
        float v = rwc * (1.0f - mm); \
        v += __shfl_xor(v, 1, 64);  v += __shfl_xor(v, 2, 64); \
        v += __shfl_xor(v, 4, 64);  v += __shfl_xor(v, 8, 64); \
        v += __shfl_xor(v, 16, 64); v += __shfl_xor(v, 32, 64); \
        CON = v; } while (0)
        FIN(0, con0); FIN(1, con1); FIN(2, con2); FIN(3, con3);
        FIN(4, con4); FIN(5, con5); FIN(6, con6); FIN(7, con7);
#undef FIN
        // sel = con[lane & 7] via cndmask mux (no dynamic register index)
        float t0 = (lane & 1) ? con1 : con0;
        float t1 = (lane & 1) ? con3 : con2;
        float t2 = (lane & 1) ? con5 : con4;
        float t3 = (lane & 1) ? con7 : con6;
        float u0 = (lane & 2) ? t1 : t0;
        float u1 = (lane & 2) ? t3 : t2;
        float sel = (lane & 4) ? u1 : u0;
        if (lane < 8)
            atomicAdd(&out[bg * BPB + lane], sel);  // 8 parallel atomics
    }
}

// ---------- fallback (ws too small): naive but correct ----------
__global__ __launch_bounds__(256) void k_naive(const float* __restrict__ x0,
                                               const float* __restrict__ conj,
                                               const float* __restrict__ rw,
                                               float* __restrict__ out) {
    int b = blockIdx.x;
    int t = threadIdx.x;
    __shared__ float red[256];
    float acc = 0.0f;
    for (int c = t; c < C_; c += 256) {
        float m = 0.0f;
        for (int v = 0; v < V_; ++v) {
            float mu1 = 1.0f / (1.0f + expf(-conj[(size_t)c * TWOV + v]));
            float mu2 = 1.0f / (1.0f + expf(-conj[(size_t)c * TWOV + V_ + v]));
            float x = x0[(size_t)b * V_ + v];
            m = fmaxf(m, fmaxf(mu1 * (1.0f - x), mu2 * x));
        }
        acc += rw[c] * (1.0f - m);
    }
    red[t] = acc;
    __syncthreads();
    for (int s = 128; s > 0; s >>= 1) {
        if (t < s) red[t] += red[t + s];
        __syncthreads();
    }
    if (t == 0) out[b] = 5.0f + red[0];
}

extern "C" void kernel_launch(void* const* d_in, const int* in_sizes, int n_in,
                              void* d_out, int out_size, void* d_ws, size_t ws_size,
                              hipStream_t stream) {
    const float* x0   = (const float*)d_in[0];
    const float* conj = (const float*)d_in[1];
    const float* rw   = (const float*)d_in[2];
    float* out = (float*)d_out;

    const size_t mu_floats = (size_t)(V_ / 2) * C_ * 4;   // 262144 floats (1 MB)
    const size_t need = mu_floats * sizeof(float);

    if (ws_size < need) {
        k_naive<<<B_, 256, 0, stream>>>(x0, conj, rw, out);
        return;
    }

    float4* muT4 = (float4*)d_ws;

    k_prep<<<C_, 256, 0, stream>>>(conj, (float2*)muT4, out);
    dim3 grid(NBG, NCH);      // 128 x 4 = 512 blocks = 2/CU, 16 waves/CU
    k_main<<<grid, 512, 0, stream>>>(x0, muT4, rw, out);
}